// Round 1
// 436.496 us; speedup vs baseline: 1.0789x; 1.0789x over previous
//
#include <hip/hip_runtime.h>
#include <hip/hip_bf16.h>
#include <stdint.h>

// Round 7: flash restructure for arithmetic intensity + pipelining.
//  - 32 q-rows/wave (2x 16-row groups): each K/V LDS fragment feeds 2 MFMAs
//    -> LDS-read bytes per MFMA halved (was the dominant per-iter cost).
//  - Double-buffered lK/lV, prefetch tile t+1 at iter start, ONE barrier
//    per iter (lP is wave-private; no barrier needed around it).
//  - Mask int32 re-reads (264 MB L2 traffic) replaced by a ballot-packed
//    bitmask (512 KB, lives in the dead wqkv_t region): 8 B/lane/masked-iter,
//    issued before the prefetch so its wait leaves prefetch in flight.
//  - s_setprio(1) around both MFMA clusters (T5).
// Block: 512 thr = 8 waves x 32 rows = 256 rows; grid (16,16) = 256 blocks.
// LDS: 2*16K (K) + 2*16K (V) + 36.9K (P) = 100 KB -> 1 block/CU.
//
// ws layout:
//   xb      [8192][1024] bf16  @ 0         (dead after qkv -> Ob)
//   wqkv_t  [3072][1024] bf16  @ 16777216  (dead after qkv -> mbits)
//   wout_t  [1024][1024] bf16  @ 23068672
//   Qs      [16][4096][128]    @ 25165824
//   Ks      [16][4096][128]    @ 41943040
//   Vt      [16][128][4096]    @ 58720256

typedef __attribute__((ext_vector_type(8))) short short8;
typedef __attribute__((ext_vector_type(4))) float f32x4;

#define SCALE_Q 0.03125f

__device__ __forceinline__ unsigned short f2bf(float f) {
  union { float f; unsigned int u; } v;
  v.f = f;
  return (unsigned short)((v.u + 0x7fffu + ((v.u >> 16) & 1u)) >> 16);
}

__device__ __forceinline__ unsigned int pkbf2(float a, float b) {
  __hip_bfloat162 h = __float22bfloat162_rn(make_float2(a, b));
  union { __hip_bfloat162 h; unsigned int u; } c;
  c.h = h;
  return c.u;
}

__device__ __forceinline__ void gload_lds16(const void* g, void* l) {
  __builtin_amdgcn_global_load_lds(
      (const __attribute__((address_space(1))) uint32_t*)(uintptr_t)g,
      (__attribute__((address_space(3))) uint32_t*)(uintptr_t)l, 16, 0, 0);
}

__device__ __forceinline__ f32x4 zero4() {
  f32x4 z; z.x = 0.f; z.y = 0.f; z.z = 0.f; z.w = 0.f; return z;
}

// ---------------- conversions ----------------
__global__ __launch_bounds__(256) void k_cvt_x(const float* __restrict__ in,
                                               unsigned short* __restrict__ out) {
  const int t = blockIdx.x * 256 + threadIdx.x;
  const float4 v = ((const float4*)in)[t];
  ushort4 o;
  o.x = f2bf(v.x); o.y = f2bf(v.y); o.z = f2bf(v.z); o.w = f2bf(v.w);
  ((ushort4*)out)[t] = o;
}

__global__ __launch_bounds__(256) void k_cvt_wt(const float* __restrict__ w,
                                                unsigned short* __restrict__ wt,
                                                int Nn) {
  __shared__ float t[32][33];
  const int n0 = blockIdx.x << 5, k0 = blockIdx.y << 5;
  const int c = threadIdx.x & 31, r8 = threadIdx.x >> 5;
#pragma unroll
  for (int i = 0; i < 4; ++i) {
    const int r = (i << 3) + r8;
    t[r][c] = w[(long)(k0 + r) * Nn + n0 + c];
  }
  __syncthreads();
#pragma unroll
  for (int i = 0; i < 4; ++i) {
    const int r = (i << 3) + r8;
    wt[(long)(n0 + r) * 1024 + k0 + c] = f2bf(t[c][r]);
  }
}

// ---------------- mask -> bitmask (ballot) ----------------
// mask[2048][2048] int32 -> mbits[2048][32] u64; bit i of word = col (64k+i).
__global__ __launch_bounds__(256) void k_mask_bits(
    const int* __restrict__ m, unsigned long long* __restrict__ mb) {
  const int t = blockIdx.x * 256 + threadIdx.x;
  const unsigned long long b = __ballot(m[t] != 0);
  if ((threadIdx.x & 63) == 0) mb[t >> 6] = b;
}

// ---------------- QKV GEMM ----------------
__global__ __launch_bounds__(256, 2) void k_qkv_gemm(
    const unsigned short* __restrict__ A,   // [8192][1024]
    const unsigned short* __restrict__ Bt,  // [3072][1024]
    unsigned short* __restrict__ Qs, unsigned short* __restrict__ Ks,
    unsigned short* __restrict__ Vt) {
  __shared__ __align__(16) unsigned short lA[4][128][8];
  __shared__ __align__(16) unsigned short lB[4][128][8];
  const int tid = threadIdx.x;
  const int w = tid >> 6, ln = tid & 63;
  const int m15 = ln & 15, q4 = ln >> 4;
  const int wm = (w >> 1) << 6, wn = (w & 1) << 6;
  const int tn = blockIdx.x, tm = blockIdx.y;
  const int which = tn >> 3;   // 0=Q 1=K 2=V (uniform per block)
  const int h = tn & 7;

  f32x4 acc[4][4];
#pragma unroll
  for (int i = 0; i < 4; ++i)
#pragma unroll
    for (int j = 0; j < 4; ++j) acc[i][j] = zero4();

  if (which == 2) {
    for (int kb = 0; kb < 1024; kb += 32) {
      __syncthreads();
#pragma unroll
      for (int c = 0; c < 2; ++c) {
        const int p = ((c * 4 + w) << 10) + (ln << 4);
        const int g = p >> 11;
        const int r = (p & 2047) >> 4;
        gload_lds16(A + ((long)tm * 128 + r) * 1024 + kb + g * 8,
                    (char*)&lA[0][0][0] + p);
        gload_lds16(Bt + ((long)tn * 128 + r) * 1024 + kb + g * 8,
                    (char*)&lB[0][0][0] + p);
      }
      __syncthreads();
      short8 afr[4], bfr[4];
#pragma unroll
      for (int i = 0; i < 4; ++i)
        afr[i] = *(const short8*)&lA[q4][wm + i * 16 + m15][0];
#pragma unroll
      for (int j = 0; j < 4; ++j)
        bfr[j] = *(const short8*)&lB[q4][wn + j * 16 + m15][0];
#pragma unroll
      for (int i = 0; i < 4; ++i)
#pragma unroll
        for (int j = 0; j < 4; ++j)
          acc[i][j] = __builtin_amdgcn_mfma_f32_16x16x32_bf16(afr[i], bfr[j],
                                                              acc[i][j], 0, 0, 0);
    }
#pragma unroll
    for (int i = 0; i < 4; ++i) {
      const int m0 = (tm << 7) + wm + (i << 4) + (q4 << 2);
      const int b = m0 >> 12, row0 = m0 & 4095;
#pragma unroll
      for (int j = 0; j < 4; ++j) {
        const int dd = wn + (j << 4) + m15;
        const long bh = b * 8 + h;
        uint2 u;
        u.x = pkbf2(acc[i][j][0], acc[i][j][1]);
        u.y = pkbf2(acc[i][j][2], acc[i][j][3]);
        *(uint2*)&Vt[(bh * 128 + dd) * 4096 + row0] = u;
      }
    }
  } else {
    for (int kb = 0; kb < 1024; kb += 32) {
      __syncthreads();
#pragma unroll
      for (int c = 0; c < 2; ++c) {
        const int p = ((c * 4 + w) << 10) + (ln << 4);
        const int g = p >> 11;
        const int r = (p & 2047) >> 4;
        gload_lds16(A + ((long)tm * 128 + r) * 1024 + kb + g * 8,
                    (char*)&lA[0][0][0] + p);
        gload_lds16(Bt + ((long)tn * 128 + r) * 1024 + kb + g * 8,
                    (char*)&lB[0][0][0] + p);
      }
      __syncthreads();
      short8 afr[4], bfr[4];
#pragma unroll
      for (int i = 0; i < 4; ++i)
        afr[i] = *(const short8*)&lA[q4][wm + i * 16 + m15][0];
#pragma unroll
      for (int j = 0; j < 4; ++j)
        bfr[j] = *(const short8*)&lB[q4][wn + j * 16 + m15][0];
#pragma unroll
      for (int i = 0; i < 4; ++i)
#pragma unroll
        for (int j = 0; j < 4; ++j)
          acc[i][j] = __builtin_amdgcn_mfma_f32_16x16x32_bf16(bfr[j], afr[i],
                                                              acc[i][j], 0, 0, 0);
    }
    unsigned short* Dst = (which == 0) ? Qs : Ks;
    const float sc = (which == 0) ? SCALE_Q : 1.0f;
#pragma unroll
    for (int i = 0; i < 4; ++i) {
      const int m = (tm << 7) + wm + (i << 4) + m15;
      const int b = m >> 12, row = m & 4095;
      const long bh = b * 8 + h;
#pragma unroll
      for (int j = 0; j < 4; ++j) {
        const int dd0 = wn + (j << 4) + (q4 << 2);
        uint2 u;
        u.x = pkbf2(acc[i][j][0] * sc, acc[i][j][1] * sc);
        u.y = pkbf2(acc[i][j][2] * sc, acc[i][j][3] * sc);
        *(uint2*)&Dst[(bh * 4096 + row) * 128 + dd0] = u;
      }
    }
  }
}

// ---------------- flash attention ----------------
// 8 waves x 32 rows = 256 rows/block, grid (16,16). Double-buffered K/V,
// prefetch-next + single barrier per iter, bitmask masking, setprio MFMA.
__global__ __launch_bounds__(512, 2) void k_flash(
    const unsigned short* __restrict__ Qs, const unsigned short* __restrict__ Ks,
    const unsigned short* __restrict__ Vt,
    const unsigned long long* __restrict__ mbits,
    unsigned short* __restrict__ Ob) {
  __shared__ __align__(16) unsigned short lK[2][16][64][8];   // 2 x 16 KB
  __shared__ __align__(16) unsigned short lV[2][8][128][8];   // 2 x 16 KB
  __shared__ __align__(16) unsigned short lP[8][2][16][72];   // 36 KB

  const int tid = threadIdx.x;
  const int w = tid >> 6, ln = tid & 63;
  const int m15 = ln & 15, q4 = ln >> 4;
  const int rowblk = blockIdx.x, bh = blockIdx.y;
  const int rbase = rowblk * 256 + w * 32;
  const int rq0 = rbase + m15;        // q-group 0 row for this lane
  const int rq1 = rbase + 16 + m15;   // q-group 1 row

  const unsigned short* Qbh = Qs + (long)bh * 524288;
  const unsigned short* Kbh = Ks + (long)bh * 524288;
  const unsigned short* Vbh = Vt + (long)bh * 524288;

  short8 qf[2][4];
#pragma unroll
  for (int kk = 0; kk < 4; ++kk) {
    qf[0][kk] = *(const short8*)(Qbh + (long)rq0 * 128 + kk * 32 + q4 * 8);
    qf[1][kk] = *(const short8*)(Qbh + (long)rq1 * 128 + kk * 32 + q4 * 8);
  }

  f32x4 o[2][8];
#pragma unroll
  for (int qg = 0; qg < 2; ++qg)
#pragma unroll
    for (int j = 0; j < 8; ++j) o[qg][j] = zero4();
  f32x4 lacc[2];
  lacc[0] = zero4(); lacc[1] = zero4();

  const bool maskblk = rowblk < 8;   // rows 0..2047

#define STAGE_KV(dst, kvoff)                                              \
  {                                                                       \
    _Pragma("unroll")                                                     \
    for (int c = 0; c < 2; ++c) {                                         \
      const int p = ((c * 8 + w) << 10) + (ln << 4);                      \
      const int cs = p >> 10;                                             \
      const int j = (p & 1023) >> 4;                                      \
      gload_lds16(Kbh + (long)((kvoff) + j) * 128 + cs * 8,               \
                  (char*)&lK[dst][0][0][0] + p);                          \
    }                                                                     \
    _Pragma("unroll")                                                     \
    for (int c = 0; c < 2; ++c) {                                         \
      const int p = ((c * 8 + w) << 10) + (ln << 4);                      \
      const int cv = p >> 11;                                             \
      const int dv = (p & 2047) >> 4;                                     \
      gload_lds16(Vbh + (long)dv * 4096 + (kvoff) + cv * 8,               \
                  (char*)&lV[dst][0][0][0] + p);                          \
    }                                                                     \
  }

  // prologue: stage tile 0 into buf 0 (syncthreads drains vmcnt)
  STAGE_KV(0, 0);
  __syncthreads();

  int cur = 0;
  for (int kv = 0; kv < 4096; kv += 64) {
    // mask words FIRST (so their wait leaves the prefetch in flight)
    unsigned long long mw0 = 0ull, mw1 = 0ull;
    const bool domask = maskblk && (kv < 2048);
    if (domask) {
      mw0 = mbits[(long)rq0 * 32 + (kv >> 6)];
      mw1 = mbits[(long)rq1 * 32 + (kv >> 6)];
    }

    // prefetch next tile into the other buffer
    const int nb = cur ^ 1;
    if (kv + 64 < 4096) STAGE_KV(nb, kv + 64);

    // S^T = K Q^T : s[qg][jt] lane layout col=m15 (q-row), row=q4*4+r (j)
    f32x4 s[2][4];
#pragma unroll
    for (int jt = 0; jt < 4; ++jt) { s[0][jt] = zero4(); s[1][jt] = zero4(); }
    __builtin_amdgcn_s_setprio(1);
#pragma unroll
    for (int jt = 0; jt < 4; ++jt) {
#pragma unroll
      for (int kk = 0; kk < 4; ++kk) {
        const short8 kfr = *(const short8*)&lK[cur][kk * 4 + q4][jt * 16 + m15][0];
        s[0][jt] = __builtin_amdgcn_mfma_f32_16x16x32_bf16(kfr, qf[0][kk],
                                                           s[0][jt], 0, 0, 0);
        s[1][jt] = __builtin_amdgcn_mfma_f32_16x16x32_bf16(kfr, qf[1][kk],
                                                           s[1][jt], 0, 0, 0);
      }
    }
    __builtin_amdgcn_s_setprio(0);

    if (domask) {
#pragma unroll
      for (int jt = 0; jt < 4; ++jt) {
        const unsigned int u0 =
            (jt & 2) ? (unsigned int)(mw0 >> 32) : (unsigned int)mw0;
        const unsigned int u1 =
            (jt & 2) ? (unsigned int)(mw1 >> 32) : (unsigned int)mw1;
        const int base = ((jt & 1) << 4) + (q4 << 2);
#pragma unroll
        for (int r = 0; r < 4; ++r) {
          if (!((u0 >> (base + r)) & 1u)) s[0][jt][r] = -1e30f;
          if (!((u1 >> (base + r)) & 1u)) s[1][jt][r] = -1e30f;
        }
      }
    }

    // p = exp(s); accumulate l; pack to wave-private LDS as PV A-frags
#pragma unroll
    for (int jt = 0; jt < 4; ++jt) {
      f32x4 p0, p1;
      p0.x = __expf(s[0][jt].x); p0.y = __expf(s[0][jt].y);
      p0.z = __expf(s[0][jt].z); p0.w = __expf(s[0][jt].w);
      p1.x = __expf(s[1][jt].x); p1.y = __expf(s[1][jt].y);
      p1.z = __expf(s[1][jt].z); p1.w = __expf(s[1][jt].w);
      lacc[0] += p0; lacc[1] += p1;
      uint2 u0, u1;
      u0.x = pkbf2(p0.x, p0.y); u0.y = pkbf2(p0.z, p0.w);
      u1.x = pkbf2(p1.x, p1.y); u1.y = pkbf2(p1.z, p1.w);
      *(uint2*)&lP[w][0][m15][jt * 16 + q4 * 4] = u0;
      *(uint2*)&lP[w][1][m15][jt * 16 + q4 * 4] = u1;
    }
    __asm__ volatile("s_waitcnt lgkmcnt(0)" ::: "memory");
    __builtin_amdgcn_sched_barrier(0);

    // O += P @ V  (each V-frag read feeds both q-groups)
    __builtin_amdgcn_s_setprio(1);
#pragma unroll
    for (int kk2 = 0; kk2 < 2; ++kk2) {
      const short8 pf0 = *(const short8*)&lP[w][0][m15][kk2 * 32 + q4 * 8];
      const short8 pf1 = *(const short8*)&lP[w][1][m15][kk2 * 32 + q4 * 8];
#pragma unroll
      for (int jt2 = 0; jt2 < 8; ++jt2) {
        const short8 vf = *(const short8*)&lV[cur][kk2 * 4 + q4][jt2 * 16 + m15][0];
        o[0][jt2] = __builtin_amdgcn_mfma_f32_16x16x32_bf16(pf0, vf,
                                                            o[0][jt2], 0, 0, 0);
        o[1][jt2] = __builtin_amdgcn_mfma_f32_16x16x32_bf16(pf1, vf,
                                                            o[1][jt2], 0, 0, 0);
      }
    }
    __builtin_amdgcn_s_setprio(0);

    // single barrier: drains this iter's prefetch (vmcnt(0) is implicit in
    // __syncthreads) -> next tile fully in LDS, prev buffer free to overwrite
    __syncthreads();
    cur = nb;
  }
#undef STAGE_KV

  const int b = bh >> 3, h = bh & 7;
#pragma unroll
  for (int qg = 0; qg < 2; ++qg) {
    float lh = lacc[qg].x + lacc[qg].y + lacc[qg].z + lacc[qg].w;
    lh += __shfl_xor(lh, 16);
    lh += __shfl_xor(lh, 32);
    const float linv = 1.0f / lh;
#pragma unroll
    for (int r = 0; r < 4; ++r) {
      const float li = __shfl(linv, q4 * 4 + r);
      const int row = rbase + qg * 16 + q4 * 4 + r;
      unsigned short* op = Ob + ((long)(b * 4096 + row)) * 1024 + h * 128;
#pragma unroll
      for (int jt2 = 0; jt2 < 8; ++jt2)
        op[jt2 * 16 + m15] = f2bf(o[qg][jt2][r] * li);
    }
  }
}

// ---------------- out projection ----------------
__global__ __launch_bounds__(256, 2) void k_proj_gemm(
    const unsigned short* __restrict__ A,   // [8192][1024]
    const unsigned short* __restrict__ Bt,  // [1024][1024]
    const float* __restrict__ bias, float* __restrict__ Out) {
  __shared__ __align__(16) unsigned short lA[4][128][8];
  __shared__ __align__(16) unsigned short lB[4][128][8];
  const int tid = threadIdx.x;
  const int w = tid >> 6, ln = tid & 63;
  const int m15 = ln & 15, q4 = ln >> 4;
  const int wm = (w >> 1) << 6, wn = (w & 1) << 6;
  const int tn = blockIdx.x, tm = blockIdx.y;

  f32x4 acc[4][4];
#pragma unroll
  for (int i = 0; i < 4; ++i)
#pragma unroll
    for (int j = 0; j < 4; ++j) acc[i][j] = zero4();

  for (int kb = 0; kb < 1024; kb += 32) {
    __syncthreads();
#pragma unroll
    for (int c = 0; c < 2; ++c) {
      const int p = ((c * 4 + w) << 10) + (ln << 4);
      const int g = p >> 11;
      const int r = (p & 2047) >> 4;
      gload_lds16(A + ((long)tm * 128 + r) * 1024 + kb + g * 8,
                  (char*)&lA[0][0][0] + p);
      gload_lds16(Bt + ((long)tn * 128 + r) * 1024 + kb + g * 8,
                  (char*)&lB[0][0][0] + p);
    }
    __syncthreads();
    short8 afr[4], bfr[4];
#pragma unroll
    for (int i = 0; i < 4; ++i)
      afr[i] = *(const short8*)&lA[q4][wm + i * 16 + m15][0];
#pragma unroll
    for (int j = 0; j < 4; ++j)
      bfr[j] = *(const short8*)&lB[q4][wn + j * 16 + m15][0];
#pragma unroll
    for (int i = 0; i < 4; ++i)
#pragma unroll
      for (int j = 0; j < 4; ++j)
        acc[i][j] = __builtin_amdgcn_mfma_f32_16x16x32_bf16(afr[i], bfr[j],
                                                            acc[i][j], 0, 0, 0);
  }

#pragma unroll
  for (int i = 0; i < 4; ++i)
#pragma unroll
    for (int r = 0; r < 4; ++r) {
      const int m = (tm << 7) + wm + (i << 4) + (q4 << 2) + r;
#pragma unroll
      for (int j = 0; j < 4; ++j) {
        const int n = (tn << 7) + wn + (j << 4) + m15;
        Out[(long)m * 1024 + n] = acc[i][j][r] + bias[n];
      }
    }
}

extern "C" void kernel_launch(void* const* d_in, const int* in_sizes, int n_in,
                              void* d_out, int out_size, void* d_ws,
                              size_t ws_size, hipStream_t stream) {
  const float* x = (const float*)d_in[0];
  const float* Wqkv = (const float*)d_in[1];
  const float* Wout = (const float*)d_in[2];
  const float* bout = (const float*)d_in[3];
  const int* mask = (const int*)d_in[4];
  float* out = (float*)d_out;

  char* ws = (char*)d_ws;
  unsigned short* xb     = (unsigned short*)(ws);            // later Ob
  unsigned short* wqkv_t = (unsigned short*)(ws + 16777216);
  unsigned short* wout_t = (unsigned short*)(ws + 23068672);
  unsigned short* Qs     = (unsigned short*)(ws + 25165824);
  unsigned short* Ks     = (unsigned short*)(ws + 41943040);
  unsigned short* Vt     = (unsigned short*)(ws + 58720256);
  unsigned short* Ob     = xb;                         // xb dead after qkv
  unsigned long long* mbits = (unsigned long long*)wqkv_t;  // wqkv_t dead after qkv

  hipLaunchKernelGGL(k_cvt_x, dim3(8192), dim3(256), 0, stream, x, xb);
  hipLaunchKernelGGL(k_cvt_wt, dim3(96, 32), dim3(256), 0, stream, Wqkv, wqkv_t, 3072);
  hipLaunchKernelGGL(k_cvt_wt, dim3(32, 32), dim3(256), 0, stream, Wout, wout_t, 1024);
  hipLaunchKernelGGL(k_qkv_gemm, dim3(24, 64), dim3(256), 0, stream,
                     xb, wqkv_t, Qs, Ks, Vt);
  hipLaunchKernelGGL(k_mask_bits, dim3(16384), dim3(256), 0, stream,
                     mask, mbits);
  hipLaunchKernelGGL(k_flash, dim3(16, 16), dim3(512), 0, stream,
                     Qs, Ks, Vt, mbits, Ob);
  hipLaunchKernelGGL(k_proj_gemm, dim3(8, 64), dim3(256), 0, stream,
                     Ob, wout_t, bout, out);
}

// Round 2
// 434.298 us; speedup vs baseline: 1.0844x; 1.0051x over previous
//
#include <hip/hip_runtime.h>
#include <hip/hip_bf16.h>
#include <stdint.h>

// Round 8: XCD-locality attack. Round 7 counters showed k_flash FETCH_SIZE
// = 245 MB == the predicted 8-XCD K/V re-fetch redundancy (16 bh x 8 XCD
// x 2 MB). Remap the flat 256-block flash grid so XCD x (= id%8 dispatch
// round-robin) owns bh {2x, 2x+1}: all 16 rowblks of a bh share one XCD's
// 4MB L2 (2 bh x 2MB K/V = 4MB resident) -> K/V fetched from HBM once per
// bh, steady-state tile loads are ~200cy L2 hits that the depth-1 prefetch
// fully covers. Same swizzle grafted onto qkv/proj grids (contiguous
// tm-chunks per XCD). Inner loops / sync structure unchanged from round 7.
//
// ws layout:
//   xb      [8192][1024] bf16  @ 0         (dead after qkv -> Ob)
//   wqkv_t  [3072][1024] bf16  @ 16777216  (dead after qkv -> mbits)
//   wout_t  [1024][1024] bf16  @ 23068672
//   Qs      [16][4096][128]    @ 25165824
//   Ks      [16][4096][128]    @ 41943040
//   Vt      [16][128][4096]    @ 58720256

typedef __attribute__((ext_vector_type(8))) short short8;
typedef __attribute__((ext_vector_type(4))) float f32x4;

#define SCALE_Q 0.03125f

__device__ __forceinline__ unsigned short f2bf(float f) {
  union { float f; unsigned int u; } v;
  v.f = f;
  return (unsigned short)((v.u + 0x7fffu + ((v.u >> 16) & 1u)) >> 16);
}

__device__ __forceinline__ unsigned int pkbf2(float a, float b) {
  __hip_bfloat162 h = __float22bfloat162_rn(make_float2(a, b));
  union { __hip_bfloat162 h; unsigned int u; } c;
  c.h = h;
  return c.u;
}

__device__ __forceinline__ void gload_lds16(const void* g, void* l) {
  __builtin_amdgcn_global_load_lds(
      (const __attribute__((address_space(1))) uint32_t*)(uintptr_t)g,
      (__attribute__((address_space(3))) uint32_t*)(uintptr_t)l, 16, 0, 0);
}

__device__ __forceinline__ f32x4 zero4() {
  f32x4 z; z.x = 0.f; z.y = 0.f; z.z = 0.f; z.w = 0.f; return z;
}

// ---------------- conversions ----------------
__global__ __launch_bounds__(256) void k_cvt_x(const float* __restrict__ in,
                                               unsigned short* __restrict__ out) {
  const int t = blockIdx.x * 256 + threadIdx.x;
  const float4 v = ((const float4*)in)[t];
  ushort4 o;
  o.x = f2bf(v.x); o.y = f2bf(v.y); o.z = f2bf(v.z); o.w = f2bf(v.w);
  ((ushort4*)out)[t] = o;
}

__global__ __launch_bounds__(256) void k_cvt_wt(const float* __restrict__ w,
                                                unsigned short* __restrict__ wt,
                                                int Nn) {
  __shared__ float t[32][33];
  const int n0 = blockIdx.x << 5, k0 = blockIdx.y << 5;
  const int c = threadIdx.x & 31, r8 = threadIdx.x >> 5;
#pragma unroll
  for (int i = 0; i < 4; ++i) {
    const int r = (i << 3) + r8;
    t[r][c] = w[(long)(k0 + r) * Nn + n0 + c];
  }
  __syncthreads();
#pragma unroll
  for (int i = 0; i < 4; ++i) {
    const int r = (i << 3) + r8;
    wt[(long)(n0 + r) * 1024 + k0 + c] = f2bf(t[c][r]);
  }
}

// ---------------- mask -> bitmask (ballot) ----------------
// mask[2048][2048] int32 -> mbits[2048][32] u64; bit i of word = col (64k+i).
__global__ __launch_bounds__(256) void k_mask_bits(
    const int* __restrict__ m, unsigned long long* __restrict__ mb) {
  const int t = blockIdx.x * 256 + threadIdx.x;
  const unsigned long long b = __ballot(m[t] != 0);
  if ((threadIdx.x & 63) == 0) mb[t >> 6] = b;
}

// ---------------- QKV GEMM ----------------
// flat grid 1536; per-XCD contiguous tm-chunk (A-panel fetched once/XCD).
__global__ __launch_bounds__(256, 2) void k_qkv_gemm(
    const unsigned short* __restrict__ A,   // [8192][1024]
    const unsigned short* __restrict__ Bt,  // [3072][1024]
    unsigned short* __restrict__ Qs, unsigned short* __restrict__ Ks,
    unsigned short* __restrict__ Vt) {
  __shared__ __align__(16) unsigned short lA[4][128][8];
  __shared__ __align__(16) unsigned short lB[4][128][8];
  const int tid = threadIdx.x;
  const int w = tid >> 6, ln = tid & 63;
  const int m15 = ln & 15, q4 = ln >> 4;
  const int wm = (w >> 1) << 6, wn = (w & 1) << 6;
  const int id = blockIdx.x;
  const int swz = (id & 7) * 192 + (id >> 3);   // XCD-chunked remap
  const int tn = swz % 24, tm = swz / 24;
  const int which = tn >> 3;   // 0=Q 1=K 2=V (uniform per block)
  const int h = tn & 7;

  f32x4 acc[4][4];
#pragma unroll
  for (int i = 0; i < 4; ++i)
#pragma unroll
    for (int j = 0; j < 4; ++j) acc[i][j] = zero4();

  if (which == 2) {
    for (int kb = 0; kb < 1024; kb += 32) {
      __syncthreads();
#pragma unroll
      for (int c = 0; c < 2; ++c) {
        const int p = ((c * 4 + w) << 10) + (ln << 4);
        const int g = p >> 11;
        const int r = (p & 2047) >> 4;
        gload_lds16(A + ((long)tm * 128 + r) * 1024 + kb + g * 8,
                    (char*)&lA[0][0][0] + p);
        gload_lds16(Bt + ((long)tn * 128 + r) * 1024 + kb + g * 8,
                    (char*)&lB[0][0][0] + p);
      }
      __syncthreads();
      short8 afr[4], bfr[4];
#pragma unroll
      for (int i = 0; i < 4; ++i)
        afr[i] = *(const short8*)&lA[q4][wm + i * 16 + m15][0];
#pragma unroll
      for (int j = 0; j < 4; ++j)
        bfr[j] = *(const short8*)&lB[q4][wn + j * 16 + m15][0];
#pragma unroll
      for (int i = 0; i < 4; ++i)
#pragma unroll
        for (int j = 0; j < 4; ++j)
          acc[i][j] = __builtin_amdgcn_mfma_f32_16x16x32_bf16(afr[i], bfr[j],
                                                              acc[i][j], 0, 0, 0);
    }
#pragma unroll
    for (int i = 0; i < 4; ++i) {
      const int m0 = (tm << 7) + wm + (i << 4) + (q4 << 2);
      const int b = m0 >> 12, row0 = m0 & 4095;
#pragma unroll
      for (int j = 0; j < 4; ++j) {
        const int dd = wn + (j << 4) + m15;
        const long bh = b * 8 + h;
        uint2 u;
        u.x = pkbf2(acc[i][j][0], acc[i][j][1]);
        u.y = pkbf2(acc[i][j][2], acc[i][j][3]);
        *(uint2*)&Vt[(bh * 128 + dd) * 4096 + row0] = u;
      }
    }
  } else {
    for (int kb = 0; kb < 1024; kb += 32) {
      __syncthreads();
#pragma unroll
      for (int c = 0; c < 2; ++c) {
        const int p = ((c * 4 + w) << 10) + (ln << 4);
        const int g = p >> 11;
        const int r = (p & 2047) >> 4;
        gload_lds16(A + ((long)tm * 128 + r) * 1024 + kb + g * 8,
                    (char*)&lA[0][0][0] + p);
        gload_lds16(Bt + ((long)tn * 128 + r) * 1024 + kb + g * 8,
                    (char*)&lB[0][0][0] + p);
      }
      __syncthreads();
      short8 afr[4], bfr[4];
#pragma unroll
      for (int i = 0; i < 4; ++i)
        afr[i] = *(const short8*)&lA[q4][wm + i * 16 + m15][0];
#pragma unroll
      for (int j = 0; j < 4; ++j)
        bfr[j] = *(const short8*)&lB[q4][wn + j * 16 + m15][0];
#pragma unroll
      for (int i = 0; i < 4; ++i)
#pragma unroll
        for (int j = 0; j < 4; ++j)
          acc[i][j] = __builtin_amdgcn_mfma_f32_16x16x32_bf16(bfr[j], afr[i],
                                                              acc[i][j], 0, 0, 0);
    }
    unsigned short* Dst = (which == 0) ? Qs : Ks;
    const float sc = (which == 0) ? SCALE_Q : 1.0f;
#pragma unroll
    for (int i = 0; i < 4; ++i) {
      const int m = (tm << 7) + wm + (i << 4) + m15;
      const int b = m >> 12, row = m & 4095;
      const long bh = b * 8 + h;
#pragma unroll
      for (int j = 0; j < 4; ++j) {
        const int dd0 = wn + (j << 4) + (q4 << 2);
        uint2 u;
        u.x = pkbf2(acc[i][j][0] * sc, acc[i][j][1] * sc);
        u.y = pkbf2(acc[i][j][2] * sc, acc[i][j][3] * sc);
        *(uint2*)&Dst[(bh * 4096 + row) * 128 + dd0] = u;
      }
    }
  }
}

// ---------------- flash attention ----------------
// 8 waves x 32 rows = 256 rows/block; flat grid 256. XCD x owns bh
// {2x,2x+1}: K/V of both (4MB) resident in that XCD's L2 -> fetch once.
__global__ __launch_bounds__(512, 2) void k_flash(
    const unsigned short* __restrict__ Qs, const unsigned short* __restrict__ Ks,
    const unsigned short* __restrict__ Vt,
    const unsigned long long* __restrict__ mbits,
    unsigned short* __restrict__ Ob) {
  __shared__ __align__(16) unsigned short lK[2][16][64][8];   // 2 x 16 KB
  __shared__ __align__(16) unsigned short lV[2][8][128][8];   // 2 x 16 KB
  __shared__ __align__(16) unsigned short lP[8][2][16][72];   // 36 KB

  const int tid = threadIdx.x;
  const int w = tid >> 6, ln = tid & 63;
  const int m15 = ln & 15, q4 = ln >> 4;
  const int id = blockIdx.x;
  const int xcd = id & 7, jj = id >> 3;
  const int bh = (xcd << 1) | (jj >> 4);   // 2 bh per XCD
  const int rowblk = jj & 15;
  const int rbase = rowblk * 256 + w * 32;
  const int rq0 = rbase + m15;        // q-group 0 row for this lane
  const int rq1 = rbase + 16 + m15;   // q-group 1 row

  const unsigned short* Qbh = Qs + (long)bh * 524288;
  const unsigned short* Kbh = Ks + (long)bh * 524288;
  const unsigned short* Vbh = Vt + (long)bh * 524288;

  short8 qf[2][4];
#pragma unroll
  for (int kk = 0; kk < 4; ++kk) {
    qf[0][kk] = *(const short8*)(Qbh + (long)rq0 * 128 + kk * 32 + q4 * 8);
    qf[1][kk] = *(const short8*)(Qbh + (long)rq1 * 128 + kk * 32 + q4 * 8);
  }

  f32x4 o[2][8];
#pragma unroll
  for (int qg = 0; qg < 2; ++qg)
#pragma unroll
    for (int j = 0; j < 8; ++j) o[qg][j] = zero4();
  f32x4 lacc[2];
  lacc[0] = zero4(); lacc[1] = zero4();

  const bool maskblk = rowblk < 8;   // rows 0..2047

#define STAGE_KV(dst, kvoff)                                              \
  {                                                                       \
    _Pragma("unroll")                                                     \
    for (int c = 0; c < 2; ++c) {                                         \
      const int p = ((c * 8 + w) << 10) + (ln << 4);                      \
      const int cs = p >> 10;                                             \
      const int j = (p & 1023) >> 4;                                      \
      gload_lds16(Kbh + (long)((kvoff) + j) * 128 + cs * 8,               \
                  (char*)&lK[dst][0][0][0] + p);                          \
    }                                                                     \
    _Pragma("unroll")                                                     \
    for (int c = 0; c < 2; ++c) {                                         \
      const int p = ((c * 8 + w) << 10) + (ln << 4);                      \
      const int cv = p >> 11;                                             \
      const int dv = (p & 2047) >> 4;                                     \
      gload_lds16(Vbh + (long)dv * 4096 + (kvoff) + cv * 8,               \
                  (char*)&lV[dst][0][0][0] + p);                          \
    }                                                                     \
  }

  // prologue: stage tile 0 into buf 0 (syncthreads drains vmcnt)
  STAGE_KV(0, 0);
  __syncthreads();

  int cur = 0;
  for (int kv = 0; kv < 4096; kv += 64) {
    // mask words FIRST (so their wait leaves the prefetch in flight)
    unsigned long long mw0 = 0ull, mw1 = 0ull;
    const bool domask = maskblk && (kv < 2048);
    if (domask) {
      mw0 = mbits[(long)rq0 * 32 + (kv >> 6)];
      mw1 = mbits[(long)rq1 * 32 + (kv >> 6)];
    }

    // prefetch next tile into the other buffer
    const int nb = cur ^ 1;
    if (kv + 64 < 4096) STAGE_KV(nb, kv + 64);

    // S^T = K Q^T : s[qg][jt] lane layout col=m15 (q-row), row=q4*4+r (j)
    f32x4 s[2][4];
#pragma unroll
    for (int jt = 0; jt < 4; ++jt) { s[0][jt] = zero4(); s[1][jt] = zero4(); }
    __builtin_amdgcn_s_setprio(1);
#pragma unroll
    for (int jt = 0; jt < 4; ++jt) {
#pragma unroll
      for (int kk = 0; kk < 4; ++kk) {
        const short8 kfr = *(const short8*)&lK[cur][kk * 4 + q4][jt * 16 + m15][0];
        s[0][jt] = __builtin_amdgcn_mfma_f32_16x16x32_bf16(kfr, qf[0][kk],
                                                           s[0][jt], 0, 0, 0);
        s[1][jt] = __builtin_amdgcn_mfma_f32_16x16x32_bf16(kfr, qf[1][kk],
                                                           s[1][jt], 0, 0, 0);
      }
    }
    __builtin_amdgcn_s_setprio(0);

    if (domask) {
#pragma unroll
      for (int jt = 0; jt < 4; ++jt) {
        const unsigned int u0 =
            (jt & 2) ? (unsigned int)(mw0 >> 32) : (unsigned int)mw0;
        const unsigned int u1 =
            (jt & 2) ? (unsigned int)(mw1 >> 32) : (unsigned int)mw1;
        const int base = ((jt & 1) << 4) + (q4 << 2);
#pragma unroll
        for (int r = 0; r < 4; ++r) {
          if (!((u0 >> (base + r)) & 1u)) s[0][jt][r] = -1e30f;
          if (!((u1 >> (base + r)) & 1u)) s[1][jt][r] = -1e30f;
        }
      }
    }

    // p = exp(s); accumulate l; pack to wave-private LDS as PV A-frags
#pragma unroll
    for (int jt = 0; jt < 4; ++jt) {
      f32x4 p0, p1;
      p0.x = __expf(s[0][jt].x); p0.y = __expf(s[0][jt].y);
      p0.z = __expf(s[0][jt].z); p0.w = __expf(s[0][jt].w);
      p1.x = __expf(s[1][jt].x); p1.y = __expf(s[1][jt].y);
      p1.z = __expf(s[1][jt].z); p1.w = __expf(s[1][jt].w);
      lacc[0] += p0; lacc[1] += p1;
      uint2 u0, u1;
      u0.x = pkbf2(p0.x, p0.y); u0.y = pkbf2(p0.z, p0.w);
      u1.x = pkbf2(p1.x, p1.y); u1.y = pkbf2(p1.z, p1.w);
      *(uint2*)&lP[w][0][m15][jt * 16 + q4 * 4] = u0;
      *(uint2*)&lP[w][1][m15][jt * 16 + q4 * 4] = u1;
    }
    __asm__ volatile("s_waitcnt lgkmcnt(0)" ::: "memory");
    __builtin_amdgcn_sched_barrier(0);

    // O += P @ V  (each V-frag read feeds both q-groups)
    __builtin_amdgcn_s_setprio(1);
#pragma unroll
    for (int kk2 = 0; kk2 < 2; ++kk2) {
      const short8 pf0 = *(const short8*)&lP[w][0][m15][kk2 * 32 + q4 * 8];
      const short8 pf1 = *(const short8*)&lP[w][1][m15][kk2 * 32 + q4 * 8];
#pragma unroll
      for (int jt2 = 0; jt2 < 8; ++jt2) {
        const short8 vf = *(const short8*)&lV[cur][kk2 * 4 + q4][jt2 * 16 + m15][0];
        o[0][jt2] = __builtin_amdgcn_mfma_f32_16x16x32_bf16(pf0, vf,
                                                            o[0][jt2], 0, 0, 0);
        o[1][jt2] = __builtin_amdgcn_mfma_f32_16x16x32_bf16(pf1, vf,
                                                            o[1][jt2], 0, 0, 0);
      }
    }
    __builtin_amdgcn_s_setprio(0);

    // single barrier: drains this iter's prefetch (vmcnt(0) is implicit in
    // __syncthreads) -> next tile fully in LDS, prev buffer free to overwrite
    __syncthreads();
    cur = nb;
  }
#undef STAGE_KV

  const int b = bh >> 3, h = bh & 7;
#pragma unroll
  for (int qg = 0; qg < 2; ++qg) {
    float lh = lacc[qg].x + lacc[qg].y + lacc[qg].z + lacc[qg].w;
    lh += __shfl_xor(lh, 16);
    lh += __shfl_xor(lh, 32);
    const float linv = 1.0f / lh;
#pragma unroll
    for (int r = 0; r < 4; ++r) {
      const float li = __shfl(linv, q4 * 4 + r);
      const int row = rbase + qg * 16 + q4 * 4 + r;
      unsigned short* op = Ob + ((long)(b * 4096 + row)) * 1024 + h * 128;
#pragma unroll
      for (int jt2 = 0; jt2 < 8; ++jt2)
        op[jt2 * 16 + m15] = f2bf(o[qg][jt2][r] * li);
    }
  }
}

// ---------------- out projection ----------------
// flat grid 512; per-XCD contiguous tm-chunk.
__global__ __launch_bounds__(256, 2) void k_proj_gemm(
    const unsigned short* __restrict__ A,   // [8192][1024]
    const unsigned short* __restrict__ Bt,  // [1024][1024]
    const float* __restrict__ bias, float* __restrict__ Out) {
  __shared__ __align__(16) unsigned short lA[4][128][8];
  __shared__ __align__(16) unsigned short lB[4][128][8];
  const int tid = threadIdx.x;
  const int w = tid >> 6, ln = tid & 63;
  const int m15 = ln & 15, q4 = ln >> 4;
  const int wm = (w >> 1) << 6, wn = (w & 1) << 6;
  const int id = blockIdx.x;
  const int swz = (id & 7) * 64 + (id >> 3);
  const int tn = swz & 7, tm = swz >> 3;

  f32x4 acc[4][4];
#pragma unroll
  for (int i = 0; i < 4; ++i)
#pragma unroll
    for (int j = 0; j < 4; ++j) acc[i][j] = zero4();

  for (int kb = 0; kb < 1024; kb += 32) {
    __syncthreads();
#pragma unroll
    for (int c = 0; c < 2; ++c) {
      const int p = ((c * 4 + w) << 10) + (ln << 4);
      const int g = p >> 11;
      const int r = (p & 2047) >> 4;
      gload_lds16(A + ((long)tm * 128 + r) * 1024 + kb + g * 8,
                  (char*)&lA[0][0][0] + p);
      gload_lds16(Bt + ((long)tn * 128 + r) * 1024 + kb + g * 8,
                  (char*)&lB[0][0][0] + p);
    }
    __syncthreads();
    short8 afr[4], bfr[4];
#pragma unroll
    for (int i = 0; i < 4; ++i)
      afr[i] = *(const short8*)&lA[q4][wm + i * 16 + m15][0];
#pragma unroll
    for (int j = 0; j < 4; ++j)
      bfr[j] = *(const short8*)&lB[q4][wn + j * 16 + m15][0];
#pragma unroll
    for (int i = 0; i < 4; ++i)
#pragma unroll
      for (int j = 0; j < 4; ++j)
        acc[i][j] = __builtin_amdgcn_mfma_f32_16x16x32_bf16(afr[i], bfr[j],
                                                            acc[i][j], 0, 0, 0);
  }

#pragma unroll
  for (int i = 0; i < 4; ++i)
#pragma unroll
    for (int r = 0; r < 4; ++r) {
      const int m = (tm << 7) + wm + (i << 4) + (q4 << 2) + r;
#pragma unroll
      for (int j = 0; j < 4; ++j) {
        const int n = (tn << 7) + wn + (j << 4) + m15;
        Out[(long)m * 1024 + n] = acc[i][j][r] + bias[n];
      }
    }
}

extern "C" void kernel_launch(void* const* d_in, const int* in_sizes, int n_in,
                              void* d_out, int out_size, void* d_ws,
                              size_t ws_size, hipStream_t stream) {
  const float* x = (const float*)d_in[0];
  const float* Wqkv = (const float*)d_in[1];
  const float* Wout = (const float*)d_in[2];
  const float* bout = (const float*)d_in[3];
  const int* mask = (const int*)d_in[4];
  float* out = (float*)d_out;

  char* ws = (char*)d_ws;
  unsigned short* xb     = (unsigned short*)(ws);            // later Ob
  unsigned short* wqkv_t = (unsigned short*)(ws + 16777216);
  unsigned short* wout_t = (unsigned short*)(ws + 23068672);
  unsigned short* Qs     = (unsigned short*)(ws + 25165824);
  unsigned short* Ks     = (unsigned short*)(ws + 41943040);
  unsigned short* Vt     = (unsigned short*)(ws + 58720256);
  unsigned short* Ob     = xb;                         // xb dead after qkv
  unsigned long long* mbits = (unsigned long long*)wqkv_t;  // wqkv_t dead after qkv

  hipLaunchKernelGGL(k_cvt_x, dim3(8192), dim3(256), 0, stream, x, xb);
  hipLaunchKernelGGL(k_cvt_wt, dim3(96, 32), dim3(256), 0, stream, Wqkv, wqkv_t, 3072);
  hipLaunchKernelGGL(k_cvt_wt, dim3(32, 32), dim3(256), 0, stream, Wout, wout_t, 1024);
  hipLaunchKernelGGL(k_qkv_gemm, dim3(1536), dim3(256), 0, stream,
                     xb, wqkv_t, Qs, Ks, Vt);
  hipLaunchKernelGGL(k_mask_bits, dim3(16384), dim3(256), 0, stream,
                     mask, mbits);
  hipLaunchKernelGGL(k_flash, dim3(256), dim3(512), 0, stream,
                     Qs, Ks, Vt, mbits, Ob);
  hipLaunchKernelGGL(k_proj_gemm, dim3(512), dim3(256), 0, stream,
                     Ob, wout_t, bout, out);
}